// Round 8
// baseline (33.582 us; speedup 1.0000x reference)
//
#include <hip/hip_runtime.h>

#define Bt 32768
#define Dt 64
#define St 16
#define Ht 128
#define At 17

typedef __attribute__((ext_vector_type(8))) short bf16x8;
typedef __attribute__((ext_vector_type(4))) float f32x4;

// ---- workspace layout (bytes) ----
#define CNT_OFF   0          // int[16]
#define PERM_OFF  128        // u16 [S][B]  (1 MiB)
#define WB_OFF    1049600    // bf16 transposed weight images [n][k], XOR-swizzled
#define OA1 0        // Wa1^T: 128 rows x 128B (K=64)
#define OA2 16384    // Wa2^T: 128 rows x 256B (K=128)
#define OA3 49152    // Wa3^T: 32-row region, rows >=17 unused garbage
#define OC1 57344    // Wc1^T
#define OC2 73728    // Wc2^T
#define SKB 106496   // per-skill stride

__device__ __forceinline__ unsigned short f2bf(float f) {
  union { float f; unsigned u; } v; v.f = f;
  unsigned r = v.u + 0x7FFFu + ((v.u >> 16) & 1u);  // RNE
  return (unsigned short)(r >> 16);
}

// packed f32x2 -> bf16x2 in one VALU op (gfx950 v_cvt_pk_bf16_f32; src0 -> lo)
__device__ __forceinline__ unsigned cvtpk(float a, float b) {
  unsigned r;
  asm("v_cvt_pk_bf16_f32 %0, %1, %2" : "=v"(r) : "v"(a), "v"(b));
  return r;
}

// tanh(acc + bias) with b2 = 2*bias precomputed: fma, exp, add, rcp, fma
__device__ __forceinline__ float tanh_fb(float acc, float b2) {
  const float t = __expf(__builtin_fmaf(acc, 2.0f, b2));  // inf-safe
  const float r = __builtin_amdgcn_rcpf(t + 1.0f);
  return __builtin_fmaf(-2.0f, r, 1.0f);
}

__device__ __forceinline__ f32x4 MFMA(bf16x8 a, bf16x8 b, f32x4 c) {
  return __builtin_amdgcn_mfma_f32_16x16x32_bf16(a, b, c, 0, 0, 0);
}

#define LGKM0() asm volatile("s_waitcnt lgkmcnt(0)" ::: "memory")

// async global->LDS, 16B/lane (R1-verified usage)
__device__ __forceinline__ void ldsload16(const char* g, char* l) {
  __builtin_amdgcn_global_load_lds(
      (const __attribute__((address_space(1))) unsigned int*)g,
      (__attribute__((address_space(3))) unsigned int*)l, 16, 0, 0);
}
// linear copy of pre-swizzled image: dest = wave-uniform base + lane*16
// (bytes/4096 instructions per wave -- uniform across waves, keeps vmcnt math exact)
__device__ __forceinline__ void stageW(const char* g, char* lds, int bytes,
                                       int wave, int lane) {
  for (int c = wave * 1024; c < bytes; c += 4096)
    ldsload16(g + c + lane * 16, lds + c);
}

// ---------- dispatch 2: fused bucket (blocks 80..207) + weight prep (blocks 0..79) ----------
// prep emits bf16 [n][k] images with byte swizzle: image[n][r] = W^T[n][(r ^ ((n&7)<<4))/2]
__global__ __launch_bounds__(256) void k_fused(
    const int* __restrict__ sid, unsigned short* __restrict__ perm,
    int* __restrict__ cnt,
    const float* __restrict__ Wa1, const float* __restrict__ Wa2,
    const float* __restrict__ Wa3, const float* __restrict__ Wc1,
    const float* __restrict__ Wc2, char* __restrict__ G) {
  __shared__ __align__(16) char smem[32768];
  const int tid = threadIdx.x;
  const int bid = blockIdx.x;

  if (bid >= 80) {
    int* lc = (int*)smem;
    int* lb = lc + St;
    const int b = (bid - 80) * 256 + tid;
    if (tid < St) lc[tid] = 0;
    __syncthreads();
    const int s = sid[b];
    const int p = atomicAdd(&lc[s], 1);
    __syncthreads();
    if (tid < St) lb[tid] = atomicAdd(&cnt[tid], lc[tid]);
    __syncthreads();
    perm[s * Bt + lb[s] + p] = (unsigned short)b;
    return;
  }

  const int s = bid / 5, mm = bid % 5;
  char* Gs = G + s * SKB;

  if (mm == 2) {  // Wa3: 128x17 -> direct swizzled scatter
    const float* src = Wa3 + s * Ht * At;
    for (int e = tid; e < Ht * At; e += 256) {
      const int k = e / At, n = e - k * At;
      *(unsigned short*)(Gs + OA3 + n * 256 + ((2 * k) ^ ((n & 7) << 4))) =
          f2bf(src[e]);
    }
    return;
  }

  const float* src; int K, off;
  if (mm == 0)      { src = Wa1 + s * Dt * Ht; K = 64;  off = OA1; }
  else if (mm == 1) { src = Wa2 + s * Ht * Ht; K = 128; off = OA2; }
  else if (mm == 3) { src = Wc1 + s * Dt * Ht; K = 64;  off = OC1; }
  else              { src = Wc2 + s * Ht * Ht; K = 128; off = OC2; }
  const int SB = 2 * K;
  const int lsb = (K == 128) ? 8 : 7;
  const int pm = (K == 128) ? 15 : 7;   // prep-internal bank-spread swizzle

  unsigned short* lds = (unsigned short*)smem;
  for (int it = 0; it < K / 8; ++it) {
    const int f = (it * 256 + tid) * 4;
    const int k = f >> 7, n0 = f & 127;
    const f32x4 v = *(const f32x4*)(src + f);
#pragma unroll
    for (int j = 0; j < 4; ++j) {
      const int n = n0 + j;
      const int byte = n * SB + ((2 * k) ^ (((n >> 2) & pm) << 4));
      lds[byte >> 1] = f2bf(v[j]);
    }
  }
  __syncthreads();
  const int nbytes = 128 * SB;
  for (int it = 0; it < nbytes / 2048; ++it) {
    const int q = (it * 256 + tid) * 8;
    const int n = q >> lsb, r = q & (SB - 1);
    const int srcoff = (r ^ ((n & 7) << 4)) ^ (((n >> 2) & pm) << 4);
    const unsigned long long v8 =
        *(const unsigned long long*)(smem + n * SB + srcoff);
    *(unsigned long long*)(Gs + off + q) = v8;
  }
}

// swizzled weight-fragment read from LDS
#define WRD(BASE, SRW, N, C) \
  (*(const bf16x8*)((BASE) + (N) * (SRW) + (((C) + lg * 16) ^ msw)))

#define STOREH(HW, t, acc, BB) { \
  const f32x4 bb_ = *(const f32x4*)((BB) + (t) * 16 + lg * 4); \
  const f32x4 b2_ = bb_ + bb_; \
  const unsigned lo_ = cvtpk(tanh_fb(acc[0], b2_[0]), tanh_fb(acc[1], b2_[1])); \
  const unsigned hi_ = cvtpk(tanh_fb(acc[2], b2_[2]), tanh_fb(acc[3], b2_[3])); \
  *(unsigned long long*)((HW) + ((32 * (t) + 8 * lg) ^ msw)) = \
      (unsigned long long)lo_ | ((unsigned long long)hi_ << 32); }

// ---------- dispatch 3: all staging issued upfront; counted vmcnt; 2 barriers ----------
__global__ __launch_bounds__(256, 2) void k_main(
    const float* __restrict__ obs,
    const float* __restrict__ ba1, const float* __restrict__ ba2,
    const float* __restrict__ ba3, const float* __restrict__ bc1,
    const float* __restrict__ bc2, const float* __restrict__ Wc3,
    const float* __restrict__ bc3,
    const int* __restrict__ cnt, const unsigned short* __restrict__ perm,
    const char* __restrict__ G, float* __restrict__ out) {
  __shared__ __align__(16) char wbuf[57344];  // L1 @0 (16K) | L2 @16K (32K) | L3 @48K (8K)
  __shared__ __align__(16) char hbuf[16384];  // 64 rows x 256B, wave-private rows

  const int tid = threadIdx.x;
  const int wave = tid >> 6, lane = tid & 63;
  const int m = lane & 15, lg = lane >> 4;
  const int bid = blockIdx.y;
  const bool actor = (blockIdx.x == 0);

  // ---- tile lookup (tile = 64 rows): in-wave prefix scan over cnt ----
  const int c16 = cnt[m];
  const int t16 = (c16 + 63) >> 6;
  int incl = t16;
#pragma unroll
  for (int d = 1; d < 16; d <<= 1) {
    const int o = __shfl_up(incl, d, 16);
    if (m >= d) incl += o;
  }
  const int total = __shfl(incl, 15, 16);
  if (bid >= total) return;
  const int excl = incl - t16;
  const unsigned long long ball = __ballot(excl <= bid);
  const int s = (int)(__popcll(ball) >> 2) - 1;
  const int excl_s = __shfl(excl, s, 16);
  const int cs = __shfl(c16, s, 16);
  const int base = (bid - excl_s) * 64;
  const int cm1 = cs - 1 - base;          // >= 0

  const unsigned short* ps = perm + s * Bt + base;
  const int myrow = ps[min(wave * 16 + m, cm1)];   // tail entries stale: clamp
  const char* Gs = G + s * SKB;

  // obs gather (oldest vmem; XB pack only waits these)
  const float* ap = obs + myrow * Dt + lg * 8;
  const f32x4 x0 = *(const f32x4*)(ap);
  const f32x4 x1 = *(const f32x4*)(ap + 4);
  const f32x4 x2 = *(const f32x4*)(ap + 32);
  const f32x4 x3 = *(const f32x4*)(ap + 36);
  asm volatile("" ::: "memory");          // pin: obs issued before staging
  if (actor) {
    stageW(Gs + OA1, wbuf, 16384, wave, lane);          // 4 instrs/wave
    asm volatile("" ::: "memory");        // pin: L1 group before phase-2 group
    stageW(Gs + OA2, wbuf + 16384, 32768, wave, lane);  // 8
    stageW(Gs + OA3, wbuf + 49152, 8192, wave, lane);   // 2
  } else {
    stageW(Gs + OC1, wbuf, 16384, wave, lane);          // 4
    asm volatile("" ::: "memory");
    stageW(Gs + OC2, wbuf + 16384, 32768, wave, lane);  // 8
  }

  union { bf16x8 v; unsigned u[4]; } XB0, XB1;
  XB0.u[0] = cvtpk(x0[0], x0[1]); XB0.u[1] = cvtpk(x0[2], x0[3]);
  XB0.u[2] = cvtpk(x1[0], x1[1]); XB0.u[3] = cvtpk(x1[2], x1[3]);
  XB1.u[0] = cvtpk(x2[0], x2[1]); XB1.u[1] = cvtpk(x2[2], x2[3]);
  XB1.u[2] = cvtpk(x3[0], x3[1]); XB1.u[3] = cvtpk(x3[2], x3[3]);

  // barrier 1: own L1 quarter staged (phase-2 loads stay in flight), all waves ready
  if (actor) asm volatile("s_waitcnt vmcnt(10)" ::: "memory");
  else       asm volatile("s_waitcnt vmcnt(8)"  ::: "memory");
  __builtin_amdgcn_s_barrier();
  __builtin_amdgcn_sched_barrier(0);

  char* hw = hbuf + (wave * 16 + m) * 256;
  const int msw = (m & 7) << 4;

  // ================= layer 1 (K=64) =================
  {
    const float* B1 = (actor ? ba1 : bc1) + s * Ht;
#pragma unroll
    for (int nt = 0; nt < 8; ++nt) {
      const bf16x8 a0 = WRD(wbuf, 128, nt * 16 + m, 0);
      const bf16x8 a1 = WRD(wbuf, 128, nt * 16 + m, 64);
      f32x4 acc = {0.f, 0.f, 0.f, 0.f};
      acc = MFMA(a0, XB0.v, acc);
      acc = MFMA(a1, XB1.v, acc);
      STOREH(hw, nt, acc, B1);
    }
  }
  LGKM0();
  const bf16x8 h0 = *(const bf16x8*)(hw + ((0   + 16 * lg) ^ msw));
  const bf16x8 h1 = *(const bf16x8*)(hw + ((64  + 16 * lg) ^ msw));
  const bf16x8 h2 = *(const bf16x8*)(hw + ((128 + 16 * lg) ^ msw));
  const bf16x8 h3 = *(const bf16x8*)(hw + ((192 + 16 * lg) ^ msw));
  // barrier 2: drain (vmcnt(0)) is wanted here -- phase-2 weights staged block-wide
  __syncthreads();

  if (actor) {
    // ================= actor layer 2 (K=128) =================
    const char* W2 = wbuf + 16384;
    const float* B2 = ba2 + s * Ht;
#pragma unroll
    for (int nt = 0; nt < 8; ++nt) {
      const int n = nt * 16 + m;
      const bf16x8 w0 = WRD(W2, 256, n, 0);
      const bf16x8 w1 = WRD(W2, 256, n, 64);
      const bf16x8 w2 = WRD(W2, 256, n, 128);
      const bf16x8 w3 = WRD(W2, 256, n, 192);
      f32x4 acc = {0.f, 0.f, 0.f, 0.f};
      acc = MFMA(w0, h0, acc); acc = MFMA(w1, h1, acc);
      acc = MFMA(w2, h2, acc); acc = MFMA(w3, h3, acc);
      STOREH(hw, nt, acc, B2);
    }
    LGKM0();
    // ================= actor layer 3 -> logits =================
    const bf16x8 H0 = *(const bf16x8*)(hw + ((0   + 16 * lg) ^ msw));
    const bf16x8 H1 = *(const bf16x8*)(hw + ((64  + 16 * lg) ^ msw));
    const bf16x8 H2 = *(const bf16x8*)(hw + ((128 + 16 * lg) ^ msw));
    const bf16x8 H3 = *(const bf16x8*)(hw + ((192 + 16 * lg) ^ msw));
    const char* W3 = wbuf + 49152;
    const bf16x8 e0 = WRD(W3, 256, m, 0);
    const bf16x8 e1 = WRD(W3, 256, m, 64);
    const bf16x8 e2 = WRD(W3, 256, m, 128);
    const bf16x8 e3 = WRD(W3, 256, m, 192);
    const bf16x8 f0 = WRD(W3, 256, 16 + m, 0);
    const bf16x8 f1 = WRD(W3, 256, 16 + m, 64);
    const bf16x8 f2 = WRD(W3, 256, 16 + m, 128);
    const bf16x8 f3 = WRD(W3, 256, 16 + m, 192);
    f32x4 p0 = {0.f, 0.f, 0.f, 0.f}, p1 = {0.f, 0.f, 0.f, 0.f};
    p0 = MFMA(e0, H0, p0); p0 = MFMA(e1, H1, p0);
    p0 = MFMA(e2, H2, p0); p0 = MFMA(e3, H3, p0);
    p1 = MFMA(f0, H0, p1); p1 = MFMA(f1, H1, p1);
    p1 = MFMA(f2, H2, p1); p1 = MFMA(f3, H3, p1);
    const float* ba3s = ba3 + s * At;
    float* o0 = out + myrow * At;
#pragma unroll
    for (int i = 0; i < 4; ++i)                 // n = 4lg+i in 0..15
      o0[4 * lg + i] = p0[i] + ba3s[4 * lg + i];
    if (lg == 0) o0[16] = p1[0] + ba3s[16];     // n = 16
  } else {
    // ================= critic layer 2 + value =================
    const char* W2 = wbuf + 16384;
    const float* B2 = bc2 + s * Ht;
    const float* w3s = Wc3 + s * Ht;
    float vp = 0.f;
#pragma unroll
    for (int nt = 0; nt < 8; ++nt) {
      const int n = nt * 16 + m;
      const bf16x8 w0 = WRD(W2, 256, n, 0);
      const bf16x8 w1 = WRD(W2, 256, n, 64);
      const bf16x8 w2 = WRD(W2, 256, n, 128);
      const bf16x8 w3 = WRD(W2, 256, n, 192);
      f32x4 acc = {0.f, 0.f, 0.f, 0.f};
      acc = MFMA(w0, h0, acc); acc = MFMA(w1, h1, acc);
      acc = MFMA(w2, h2, acc); acc = MFMA(w3, h3, acc);
      const f32x4 bb = *(const f32x4*)(B2 + nt * 16 + lg * 4);
      const f32x4 b2 = bb + bb;
      const f32x4 wv = *(const f32x4*)(w3s + nt * 16 + lg * 4);
#pragma unroll
      for (int i = 0; i < 4; ++i)
        vp = __builtin_fmaf(tanh_fb(acc[i], b2[i]), wv[i], vp);
    }
    vp += __shfl_xor(vp, 16);
    vp += __shfl_xor(vp, 32);
    if (lane < 16) out[Bt * At + myrow] = vp + bc3[s];
  }
}

extern "C" void kernel_launch(void* const* d_in, const int* in_sizes, int n_in,
                              void* d_out, int out_size, void* d_ws, size_t ws_size,
                              hipStream_t stream) {
  const float* obs = (const float*)d_in[0];
  const int* sid   = (const int*)d_in[1];
  const float* Wa1 = (const float*)d_in[2];
  const float* ba1 = (const float*)d_in[3];
  const float* Wa2 = (const float*)d_in[4];
  const float* ba2 = (const float*)d_in[5];
  const float* Wa3 = (const float*)d_in[6];
  const float* ba3 = (const float*)d_in[7];
  const float* Wc1 = (const float*)d_in[8];
  const float* bc1 = (const float*)d_in[9];
  const float* Wc2 = (const float*)d_in[10];
  const float* bc2 = (const float*)d_in[11];
  const float* Wc3 = (const float*)d_in[12];
  const float* bc3 = (const float*)d_in[13];
  float* out = (float*)d_out;
  char* ws = (char*)d_ws;

  int* cnt = (int*)(ws + CNT_OFF);
  unsigned short* perm = (unsigned short*)(ws + PERM_OFF);
  char* G = ws + WB_OFF;

  hipMemsetAsync(cnt, 0, St * sizeof(int), stream);
  k_fused<<<dim3(208), dim3(256), 0, stream>>>(sid, perm, cnt, Wa1, Wa2, Wa3, Wc1, Wc2, G);
  k_main<<<dim3(2, 528), dim3(256), 0, stream>>>(
      obs, ba1, ba2, ba3, bc1, bc2, Wc3, bc3, cnt, perm, G, out);
}

// Round 9
// 27.830 us; speedup vs baseline: 1.2067x; 1.2067x over previous
//
#include <hip/hip_runtime.h>

#define Bt 32768
#define Dt 64
#define St 16
#define Ht 128
#define At 17

typedef __attribute__((ext_vector_type(8))) short bf16x8;
typedef __attribute__((ext_vector_type(4))) float f32x4;

// ---- workspace layout (bytes) ----
#define CNT_OFF   0          // int[16]
#define PERM_OFF  128        // u16 [S][B]  (1 MiB)
#define WB_OFF    1049600    // bf16 transposed weight images [n][k], XOR-swizzled
#define OA1 0        // Wa1^T: 128 rows x 128B (K=64)
#define OA2 16384    // Wa2^T: 128 rows x 256B (K=128)
#define OA3 49152    // Wa3^T: 32-row region, rows >=17 unused garbage
#define OC1 57344    // Wc1^T
#define OC2 73728    // Wc2^T
#define SKB 106496   // per-skill stride

__device__ __forceinline__ unsigned short f2bf(float f) {
  union { float f; unsigned u; } v; v.f = f;
  unsigned r = v.u + 0x7FFFu + ((v.u >> 16) & 1u);  // RNE
  return (unsigned short)(r >> 16);
}

// packed f32x2 -> bf16x2 in one VALU op (gfx950 v_cvt_pk_bf16_f32; src0 -> lo)
__device__ __forceinline__ unsigned cvtpk(float a, float b) {
  unsigned r;
  asm("v_cvt_pk_bf16_f32 %0, %1, %2" : "=v"(r) : "v"(a), "v"(b));
  return r;
}

// tanh(acc + bias) with b2 = 2*bias precomputed: fma, exp, add, rcp, fma
__device__ __forceinline__ float tanh_fb(float acc, float b2) {
  const float t = __expf(__builtin_fmaf(acc, 2.0f, b2));  // inf-safe
  const float r = __builtin_amdgcn_rcpf(t + 1.0f);
  return __builtin_fmaf(-2.0f, r, 1.0f);
}

__device__ __forceinline__ f32x4 MFMA(bf16x8 a, bf16x8 b, f32x4 c) {
  return __builtin_amdgcn_mfma_f32_16x16x32_bf16(a, b, c, 0, 0, 0);
}

#define LGKM0() asm volatile("s_waitcnt lgkmcnt(0)" ::: "memory")

// async global->LDS, 16B/lane
__device__ __forceinline__ void ldsload16(const char* g, char* l) {
  __builtin_amdgcn_global_load_lds(
      (const __attribute__((address_space(1))) unsigned int*)g,
      (__attribute__((address_space(3))) unsigned int*)l, 16, 0, 0);
}
// linear copy of pre-swizzled image: dest = wave-uniform base + lane*16
__device__ __forceinline__ void stageW(const char* g, char* lds, int bytes,
                                       int wave, int lane) {
  for (int c = wave * 1024; c < bytes; c += 4096)
    ldsload16(g + c + lane * 16, lds + c);
}

// ---------- dispatch 2: fused bucket (blocks 80..207) + weight prep (blocks 0..79) ----------
__global__ __launch_bounds__(256) void k_fused(
    const int* __restrict__ sid, unsigned short* __restrict__ perm,
    int* __restrict__ cnt,
    const float* __restrict__ Wa1, const float* __restrict__ Wa2,
    const float* __restrict__ Wa3, const float* __restrict__ Wc1,
    const float* __restrict__ Wc2, char* __restrict__ G) {
  __shared__ __align__(16) char smem[32768];
  const int tid = threadIdx.x;
  const int bid = blockIdx.x;

  if (bid >= 80) {
    int* lc = (int*)smem;
    int* lb = lc + St;
    const int b = (bid - 80) * 256 + tid;
    if (tid < St) lc[tid] = 0;
    __syncthreads();
    const int s = sid[b];
    const int p = atomicAdd(&lc[s], 1);
    __syncthreads();
    if (tid < St) lb[tid] = atomicAdd(&cnt[tid], lc[tid]);
    __syncthreads();
    perm[s * Bt + lb[s] + p] = (unsigned short)b;
    return;
  }

  const int s = bid / 5, mm = bid % 5;
  char* Gs = G + s * SKB;

  if (mm == 2) {  // Wa3: 128x17 -> direct swizzled scatter
    const float* src = Wa3 + s * Ht * At;
    for (int e = tid; e < Ht * At; e += 256) {
      const int k = e / At, n = e - k * At;
      *(unsigned short*)(Gs + OA3 + n * 256 + ((2 * k) ^ ((n & 7) << 4))) =
          f2bf(src[e]);
    }
    return;
  }

  const float* src; int K, off;
  if (mm == 0)      { src = Wa1 + s * Dt * Ht; K = 64;  off = OA1; }
  else if (mm == 1) { src = Wa2 + s * Ht * Ht; K = 128; off = OA2; }
  else if (mm == 3) { src = Wc1 + s * Dt * Ht; K = 64;  off = OC1; }
  else              { src = Wc2 + s * Ht * Ht; K = 128; off = OC2; }
  const int SB = 2 * K;
  const int lsb = (K == 128) ? 8 : 7;
  const int pm = (K == 128) ? 15 : 7;

  unsigned short* lds = (unsigned short*)smem;
  for (int it = 0; it < K / 8; ++it) {
    const int f = (it * 256 + tid) * 4;
    const int k = f >> 7, n0 = f & 127;
    const f32x4 v = *(const f32x4*)(src + f);
#pragma unroll
    for (int j = 0; j < 4; ++j) {
      const int n = n0 + j;
      const int byte = n * SB + ((2 * k) ^ (((n >> 2) & pm) << 4));
      lds[byte >> 1] = f2bf(v[j]);
    }
  }
  __syncthreads();
  const int nbytes = 128 * SB;
  for (int it = 0; it < nbytes / 2048; ++it) {
    const int q = (it * 256 + tid) * 8;
    const int n = q >> lsb, r = q & (SB - 1);
    const int srcoff = (r ^ ((n & 7) << 4)) ^ (((n >> 2) & pm) << 4);
    const unsigned long long v8 =
        *(const unsigned long long*)(smem + n * SB + srcoff);
    *(unsigned long long*)(Gs + off + q) = v8;
  }
}

__device__ __forceinline__ bf16x8 wrd(const char* base, int srw, int n, int c,
                                      int lg, int msw) {
  return *(const bf16x8*)(base + n * srw + (((c) + lg * 16) ^ msw));
}

__device__ __forceinline__ void storeh(char* hw, int msw, int lg, int t,
                                       const f32x4 acc, const float* BB) {
  const f32x4 bb = *(const f32x4*)(BB + t * 16 + lg * 4);
  const f32x4 b2 = bb + bb;
  const unsigned lo = cvtpk(tanh_fb(acc[0], b2[0]), tanh_fb(acc[1], b2[1]));
  const unsigned hi = cvtpk(tanh_fb(acc[2], b2[2]), tanh_fb(acc[3], b2[3]));
  *(unsigned long long*)(hw + ((32 * t + 8 * lg) ^ msw)) =
      (unsigned long long)lo | ((unsigned long long)hi << 32);
}

// ---- one 64-row tile, actor role: L1 -> L2 -> L3 -> logits ----
__device__ __forceinline__ void tile_actor(
    int tbase, int rnext, bool dopref, int& rowcur,
    f32x4& cx0, f32x4& cx1, f32x4& cx2, f32x4& cx3,
    const char* wbuf, char* hw, const float* obs,
    const float* ba1s, const float* ba2s, const float* ba3s, float* out,
    int m, int lg, int msw, int wm, int cs) {
  union { bf16x8 v; unsigned u[4]; } XB0, XB1;
  XB0.u[0] = cvtpk(cx0[0], cx0[1]); XB0.u[1] = cvtpk(cx0[2], cx0[3]);
  XB0.u[2] = cvtpk(cx1[0], cx1[1]); XB0.u[3] = cvtpk(cx1[2], cx1[3]);
  XB1.u[0] = cvtpk(cx2[0], cx2[1]); XB1.u[1] = cvtpk(cx2[2], cx2[3]);
  XB1.u[2] = cvtpk(cx3[0], cx3[1]); XB1.u[3] = cvtpk(cx3[2], cx3[3]);
  const int myrow = rowcur;
  if (dopref) {  // next tile's obs: in flight across this tile's compute
    const float* ap = obs + rnext * Dt + lg * 8;
    cx0 = *(const f32x4*)(ap);      cx1 = *(const f32x4*)(ap + 4);
    cx2 = *(const f32x4*)(ap + 32); cx3 = *(const f32x4*)(ap + 36);
  }
  rowcur = rnext;
  // L1 (K=64)
#pragma unroll
  for (int nt = 0; nt < 8; ++nt) {
    const bf16x8 a0 = wrd(wbuf, 128, nt * 16 + m, 0, lg, msw);
    const bf16x8 a1 = wrd(wbuf, 128, nt * 16 + m, 64, lg, msw);
    f32x4 acc = {0.f, 0.f, 0.f, 0.f};
    acc = MFMA(a0, XB0.v, acc);
    acc = MFMA(a1, XB1.v, acc);
    storeh(hw, msw, lg, nt, acc, ba1s);
  }
  LGKM0();
  const bf16x8 h0 = *(const bf16x8*)(hw + ((0   + 16 * lg) ^ msw));
  const bf16x8 h1 = *(const bf16x8*)(hw + ((64  + 16 * lg) ^ msw));
  const bf16x8 h2 = *(const bf16x8*)(hw + ((128 + 16 * lg) ^ msw));
  const bf16x8 h3 = *(const bf16x8*)(hw + ((192 + 16 * lg) ^ msw));
  // L2 (K=128)
#pragma unroll
  for (int nt = 0; nt < 8; ++nt) {
    const int n = nt * 16 + m;
    const bf16x8 w0 = wrd(wbuf + 16384, 256, n, 0, lg, msw);
    const bf16x8 w1 = wrd(wbuf + 16384, 256, n, 64, lg, msw);
    const bf16x8 w2 = wrd(wbuf + 16384, 256, n, 128, lg, msw);
    const bf16x8 w3 = wrd(wbuf + 16384, 256, n, 192, lg, msw);
    f32x4 acc = {0.f, 0.f, 0.f, 0.f};
    acc = MFMA(w0, h0, acc); acc = MFMA(w1, h1, acc);
    acc = MFMA(w2, h2, acc); acc = MFMA(w3, h3, acc);
    storeh(hw, msw, lg, nt, acc, ba2s);
  }
  LGKM0();
  const bf16x8 H0 = *(const bf16x8*)(hw + ((0   + 16 * lg) ^ msw));
  const bf16x8 H1 = *(const bf16x8*)(hw + ((64  + 16 * lg) ^ msw));
  const bf16x8 H2 = *(const bf16x8*)(hw + ((128 + 16 * lg) ^ msw));
  const bf16x8 H3 = *(const bf16x8*)(hw + ((192 + 16 * lg) ^ msw));
  // L3
  const char* W3 = wbuf + 49152;
  const bf16x8 e0 = wrd(W3, 256, m, 0, lg, msw);
  const bf16x8 e1 = wrd(W3, 256, m, 64, lg, msw);
  const bf16x8 e2 = wrd(W3, 256, m, 128, lg, msw);
  const bf16x8 e3 = wrd(W3, 256, m, 192, lg, msw);
  const bf16x8 f0 = wrd(W3, 256, 16 + m, 0, lg, msw);
  const bf16x8 f1 = wrd(W3, 256, 16 + m, 64, lg, msw);
  const bf16x8 f2 = wrd(W3, 256, 16 + m, 128, lg, msw);
  const bf16x8 f3 = wrd(W3, 256, 16 + m, 192, lg, msw);
  f32x4 p0 = {0.f, 0.f, 0.f, 0.f}, p1 = {0.f, 0.f, 0.f, 0.f};
  p0 = MFMA(e0, H0, p0); p0 = MFMA(e1, H1, p0);
  p0 = MFMA(e2, H2, p0); p0 = MFMA(e3, H3, p0);
  p1 = MFMA(f0, H0, p1); p1 = MFMA(f1, H1, p1);
  p1 = MFMA(f2, H2, p1); p1 = MFMA(f3, H3, p1);
  if (tbase + wm < cs) {
    float* orow = out + myrow * At;
#pragma unroll
    for (int i = 0; i < 4; ++i)                 // n = 4lg+i in 0..15
      orow[4 * lg + i] = p0[i] + ba3s[4 * lg + i];
    if (lg == 0) orow[16] = p1[0] + ba3s[16];   // n = 16
  }
}

// ---- one 64-row tile, critic role: C1 -> C2 -> value ----
__device__ __forceinline__ void tile_critic(
    int tbase, int rnext, bool dopref, int& rowcur,
    f32x4& cx0, f32x4& cx1, f32x4& cx2, f32x4& cx3,
    const char* wbuf, char* hw, const float* obs,
    const float* bc1s, const float* bc2s, const float* wc3s, float bc3s,
    float* out, int m, int lg, int msw, int wm, int cs) {
  union { bf16x8 v; unsigned u[4]; } XB0, XB1;
  XB0.u[0] = cvtpk(cx0[0], cx0[1]); XB0.u[1] = cvtpk(cx0[2], cx0[3]);
  XB0.u[2] = cvtpk(cx1[0], cx1[1]); XB0.u[3] = cvtpk(cx1[2], cx1[3]);
  XB1.u[0] = cvtpk(cx2[0], cx2[1]); XB1.u[1] = cvtpk(cx2[2], cx2[3]);
  XB1.u[2] = cvtpk(cx3[0], cx3[1]); XB1.u[3] = cvtpk(cx3[2], cx3[3]);
  const int myrow = rowcur;
  if (dopref) {
    const float* ap = obs + rnext * Dt + lg * 8;
    cx0 = *(const f32x4*)(ap);      cx1 = *(const f32x4*)(ap + 4);
    cx2 = *(const f32x4*)(ap + 32); cx3 = *(const f32x4*)(ap + 36);
  }
  rowcur = rnext;
  // C1 (K=64)
#pragma unroll
  for (int nt = 0; nt < 8; ++nt) {
    const bf16x8 a0 = wrd(wbuf, 128, nt * 16 + m, 0, lg, msw);
    const bf16x8 a1 = wrd(wbuf, 128, nt * 16 + m, 64, lg, msw);
    f32x4 acc = {0.f, 0.f, 0.f, 0.f};
    acc = MFMA(a0, XB0.v, acc);
    acc = MFMA(a1, XB1.v, acc);
    storeh(hw, msw, lg, nt, acc, bc1s);
  }
  LGKM0();
  const bf16x8 h0 = *(const bf16x8*)(hw + ((0   + 16 * lg) ^ msw));
  const bf16x8 h1 = *(const bf16x8*)(hw + ((64  + 16 * lg) ^ msw));
  const bf16x8 h2 = *(const bf16x8*)(hw + ((128 + 16 * lg) ^ msw));
  const bf16x8 h3 = *(const bf16x8*)(hw + ((192 + 16 * lg) ^ msw));
  // C2 + value
  float vp = 0.f;
#pragma unroll
  for (int nt = 0; nt < 8; ++nt) {
    const int n = nt * 16 + m;
    const bf16x8 w0 = wrd(wbuf + 16384, 256, n, 0, lg, msw);
    const bf16x8 w1 = wrd(wbuf + 16384, 256, n, 64, lg, msw);
    const bf16x8 w2 = wrd(wbuf + 16384, 256, n, 128, lg, msw);
    const bf16x8 w3 = wrd(wbuf + 16384, 256, n, 192, lg, msw);
    f32x4 acc = {0.f, 0.f, 0.f, 0.f};
    acc = MFMA(w0, h0, acc); acc = MFMA(w1, h1, acc);
    acc = MFMA(w2, h2, acc); acc = MFMA(w3, h3, acc);
    const f32x4 bb = *(const f32x4*)(bc2s + nt * 16 + lg * 4);
    const f32x4 b2 = bb + bb;
    const f32x4 wv = *(const f32x4*)(wc3s + nt * 16 + lg * 4);
#pragma unroll
    for (int i = 0; i < 4; ++i)
      vp = __builtin_fmaf(tanh_fb(acc[i], b2[i]), wv[i], vp);
  }
  vp += __shfl_xor(vp, 16);
  vp += __shfl_xor(vp, 32);
  if ((m == (threadIdx.x & 63)) && (threadIdx.x & 63) < 16) {  // lane<16
    if (tbase + wm < cs) out[Bt * At + myrow] = vp + bc3s;
  }
}

// ---------- dispatch 3: persistent per-(skill,role) blocks; staged once; pipelined ----------
__global__ __launch_bounds__(256, 2) void k_main(
    const float* __restrict__ obs,
    const float* __restrict__ ba1, const float* __restrict__ ba2,
    const float* __restrict__ ba3, const float* __restrict__ bc1,
    const float* __restrict__ bc2, const float* __restrict__ Wc3,
    const float* __restrict__ bc3,
    const int* __restrict__ cnt, const unsigned short* __restrict__ perm,
    const char* __restrict__ G, float* __restrict__ out) {
  __shared__ __align__(16) char wbuf[57344];  // L1@0 16K | L2@16K 32K | L3@48K 8K
  __shared__ __align__(16) char hbuf[16384];  // 64 rows x 256B, wave-private rows

  const int tid = threadIdx.x;
  const int wave = tid >> 6, lane = tid & 63;
  const int m = lane & 15, lg = lane >> 4;
  const bool actor = (blockIdx.x == 0);
  const int s = blockIdx.y, idx = blockIdx.z;
  const char* Gs = G + s * SKB;
  const int wm = wave * 16 + m;

  // perm for this block's (up to 3) tiles: addresses need no cnt -> issue first
  const unsigned short* pb = perm + s * Bt;
  int r0 = pb[idx * 64 + wm];
  int r1 = pb[(idx + 16) * 64 + wm];
  int r2 = pb[(idx + 32) * 64 + wm];
  const int cs = cnt[s];                 // scalar, parallel with the above

  // stage all weights ONCE (issue immediately; waited by the single barrier)
  if (actor) {
    stageW(Gs + OA1, wbuf, 16384, wave, lane);
    stageW(Gs + OA2, wbuf + 16384, 32768, wave, lane);
    stageW(Gs + OA3, wbuf + 49152, 8192, wave, lane);
  } else {
    stageW(Gs + OC1, wbuf, 16384, wave, lane);
    stageW(Gs + OC2, wbuf + 16384, 32768, wave, lane);
  }

  r0 = min(r0, Bt - 1); r1 = min(r1, Bt - 1); r2 = min(r2, Bt - 1);  // stale guard
  const int nt = (cs + 63) >> 6;

  // obs for tile 0
  f32x4 cx0, cx1, cx2, cx3;
  {
    const float* ap = obs + r0 * Dt + lg * 8;
    cx0 = *(const f32x4*)(ap);      cx1 = *(const f32x4*)(ap + 4);
    cx2 = *(const f32x4*)(ap + 32); cx3 = *(const f32x4*)(ap + 36);
  }

  char* hw = hbuf + wm * 256;
  const int msw = (m & 7) << 4;
  __syncthreads();                       // the ONLY barrier: weights + obs drained

  int rowcur = r0;
  if (actor) {
    const float* ba1s = ba1 + s * Ht;
    const float* ba2s = ba2 + s * Ht;
    const float* ba3s = ba3 + s * At;
    tile_actor(idx * 64, r1, true, rowcur, cx0, cx1, cx2, cx3,
               wbuf, hw, obs, ba1s, ba2s, ba3s, out, m, lg, msw, wm, cs);
    if ((idx + 16) * 64 < cs + 63 && idx + 16 < nt)
      tile_actor((idx + 16) * 64, r2, true, rowcur, cx0, cx1, cx2, cx3,
                 wbuf, hw, obs, ba1s, ba2s, ba3s, out, m, lg, msw, wm, cs);
    if (idx + 32 < nt)
      tile_actor((idx + 32) * 64, r2, false, rowcur, cx0, cx1, cx2, cx3,
                 wbuf, hw, obs, ba1s, ba2s, ba3s, out, m, lg, msw, wm, cs);
  } else {
    const float* bc1s = bc1 + s * Ht;
    const float* bc2s = bc2 + s * Ht;
    const float* wc3s = Wc3 + s * Ht;
    const float bc3s = bc3[s];
    tile_critic(idx * 64, r1, true, rowcur, cx0, cx1, cx2, cx3,
                wbuf, hw, obs, bc1s, bc2s, wc3s, bc3s, out, m, lg, msw, wm, cs);
    if (idx + 16 < nt)
      tile_critic((idx + 16) * 64, r2, true, rowcur, cx0, cx1, cx2, cx3,
                  wbuf, hw, obs, bc1s, bc2s, wc3s, bc3s, out, m, lg, msw, wm, cs);
    if (idx + 32 < nt)
      tile_critic((idx + 32) * 64, r2, false, rowcur, cx0, cx1, cx2, cx3,
                  wbuf, hw, obs, bc1s, bc2s, wc3s, bc3s, out, m, lg, msw, wm, cs);
  }
}

extern "C" void kernel_launch(void* const* d_in, const int* in_sizes, int n_in,
                              void* d_out, int out_size, void* d_ws, size_t ws_size,
                              hipStream_t stream) {
  const float* obs = (const float*)d_in[0];
  const int* sid   = (const int*)d_in[1];
  const float* Wa1 = (const float*)d_in[2];
  const float* ba1 = (const float*)d_in[3];
  const float* Wa2 = (const float*)d_in[4];
  const float* ba2 = (const float*)d_in[5];
  const float* Wa3 = (const float*)d_in[6];
  const float* ba3 = (const float*)d_in[7];
  const float* Wc1 = (const float*)d_in[8];
  const float* bc1 = (const float*)d_in[9];
  const float* Wc2 = (const float*)d_in[10];
  const float* bc2 = (const float*)d_in[11];
  const float* Wc3 = (const float*)d_in[12];
  const float* bc3 = (const float*)d_in[13];
  float* out = (float*)d_out;
  char* ws = (char*)d_ws;

  int* cnt = (int*)(ws + CNT_OFF);
  unsigned short* perm = (unsigned short*)(ws + PERM_OFF);
  char* G = ws + WB_OFF;

  hipMemsetAsync(cnt, 0, St * sizeof(int), stream);
  k_fused<<<dim3(208), dim3(256), 0, stream>>>(sid, perm, cnt, Wa1, Wa2, Wa3, Wc1, Wc2, G);
  k_main<<<dim3(2, 16, 16), dim3(256), 0, stream>>>(
      obs, ba1, ba2, ba3, bc1, bc2, Wc3, bc3, cnt, perm, G, out);
}